// Round 2
// baseline (364.049 us; speedup 1.0000x reference)
//
#include <hip/hip_runtime.h>

// MC3DAD kNN(k=5) covariance-trace curvature. B=8, N=4096, f32.
// Round 5: occupancy + per-lane restructure.
//  (1) 64 queries/block -> 512 blocks, 2 blocks/CU, 16 waves/CU (4/SIMD):
//      2x the latency hiding of round 4's 1-block/CU launch.
//  (2) Q=4 queries per lane x G=32 segments (SEGLEN=128): each candidate
//      ds_read_b128 feeds 4 pairs -> 128 reads/lane (was 512), ~20 VALU
//      between reads.
//  (3) Queries pre-scaled by -2: filter = 3 chained fma + cmp + mask-add
//      (5 VALU/pair). New rounding tree error <= ~2.5e-5, well inside the
//      proven 6e-5 margin.
//  (4) Seeded warm-up: exact-push first 8 candidates/lane, share tau
//      (5th-of-256), then 4 filtered chunks. No keep-everything drain.
//  Selection machinery bit-identical to rounds 3-4 (absmax 0.0): exact
//  numpy-tree dd recompute, strict-< push5 in ascending index order, final
//  ranking by packed (sqrt-dist, idx) u64 keys, same epilogue arithmetic.

typedef unsigned long long ull;

constexpr int N_PTS  = 4096;
constexpr int BATCH  = 8;
constexpr int KNN    = 5;
constexpr int NQ     = 4;               // queries per lane (register Q)
constexpr int GSEG   = 32;              // segments (s = lane>>1)
constexpr int SEGLEN = N_PTS / GSEG;    // 128 candidates per lane
constexpr int NTHR   = 512;             // 8 waves
constexpr int QPW    = 2 * NQ;          // 8 queries per wave (j = lane&1)
constexpr int QPB    = (NTHR / 64) * QPW;   // 64 queries per block

__device__ __forceinline__ int swz(int j) { return j + (j >> 9); } // +16B/512pts

__device__ __forceinline__ ull umin64(ull a, ull b) { return a < b ? a : b; }
__device__ __forceinline__ ull umax64(ull a, ull b) { return a < b ? b : a; }

// Branchless stable insert of (dd,idx) into ascending 5-list (strict <).
// Callers guarantee ascending-index insertion order, so equal-dd entries
// stay in index order (matches jax.lax.top_k stability).
__device__ __forceinline__ void push5(float dd, int idx,
                                      float d[KNN], int ix[KNN])
{
    float ad = dd; int ai = idx;
    #pragma unroll
    for (int p = 0; p < KNN - 1; ++p) {
        const bool lt = ad < d[p];
        const float md = lt ? ad : d[p];
        const int   mi = lt ? ai : ix[p];
        const float xd = lt ? d[p] : ad;
        const int   xi = lt ? ix[p] : ai;
        d[p] = md; ix[p] = mi; ad = xd; ai = xi;
    }
    const bool lt = ad < d[KNN - 1];
    d[KNN - 1]  = lt ? ad : d[KNN - 1];
    ix[KNN - 1] = lt ? ai : ix[KNN - 1];
}

// Merge two ascending sorted 5-lists (u64 lex keys) -> ascending top-5.
__device__ __forceinline__ void merge5(ull a[KNN], const ull b[KNN])
{
    const ull r0 = umin64(a[0], b[0]);
    const ull r1 = umin64(umin64(a[1], b[1]), umax64(a[0], b[0]));
    const ull r2 = umin64(umin64(a[2], b[2]),
                          umin64(umax64(a[1], b[0]), umax64(a[0], b[1])));
    const ull r3 = umin64(umin64(a[3], b[3]),
                   umin64(umax64(a[2], b[0]),
                   umin64(umax64(a[1], b[1]), umax64(a[0], b[2]))));
    const ull r4 = umin64(umin64(a[4], b[4]),
                   umin64(umin64(umax64(a[3], b[0]), umax64(a[2], b[1])),
                          umin64(umax64(a[1], b[2]), umax64(a[0], b[3]))));
    a[0] = r0; a[1] = r1; a[2] = r2; a[3] = r3; a[4] = r4;
}

__device__ __forceinline__ void sort5(ull key[KNN])
{
    #pragma unroll
    for (int i = 0; i < KNN - 1; ++i)
        #pragma unroll
        for (int p = 0; p < KNN - 1 - i; ++p) {
            const ull lo = umin64(key[p], key[p + 1]);
            const ull hi = umax64(key[p], key[p + 1]);
            key[p] = lo; key[p + 1] = hi;
        }
}

// Filtered scan over LEN candidates (4-batched loads). Masks accumulate
// MSB-first: after LEN shifts, bit (LEN-1-u) holds candidate u.
// a[q] = (-2*qx, -2*qy, -2*qz); f = fma(ax,cx, fma(ay,cy, fma(az,cz, cw)))
// approximates dd - qw; tau is the lagged inflated threshold.
template<int LEN>
__device__ __forceinline__ void scan_chunk(const float4* __restrict__ seg, int start,
                                           const float4 a[NQ], const float tau[NQ],
                                           unsigned m[NQ])
{
    #pragma unroll
    for (int q = 0; q < NQ; ++q) m[q] = 0u;
    #pragma unroll
    for (int g = 0; g < LEN; g += 4) {
        float4 cb[4];
        #pragma unroll
        for (int u = 0; u < 4; ++u) cb[u] = seg[start + g + u];
        #pragma unroll
        for (int u = 0; u < 4; ++u) {
            #pragma unroll
            for (int q = 0; q < NQ; ++q) {
                const float f = fmaf(a[q].x, cb[u].x,
                                fmaf(a[q].y, cb[u].y,
                                fmaf(a[q].z, cb[u].z, cb[u].w)));
                m[q] = (m[q] << 1) | (f < tau[q] ? 1u : 0u);
            }
        }
    }
}

// Drain bit-reversed keep masks for all 4 queries. ctz over the reversed
// mask walks candidates in ascending index order. Exact numpy-tree dd
// recompute, identical to the proven round-3/4 drain.
__device__ __forceinline__ void drain4(unsigned r[NQ], int base,
                                       const float4 p[NQ],
                                       float d[NQ][KNN], int ix[NQ][KNN],
                                       const float4* __restrict__ pts)
{
    while (__any((r[0] | r[1] | r[2] | r[3]) != 0u)) {
        #pragma unroll
        for (int q = 0; q < NQ; ++q) {
            if (r[q]) {
                const int bpos = __builtin_ctz(r[q]);
                r[q] &= r[q] - 1;
                const int idx = base + bpos;
                const float4 c = pts[swz(idx)];
                const float dot = __fadd_rn(__fadd_rn(__fmul_rn(p[q].x, c.x),
                                                      __fmul_rn(p[q].y, c.y)),
                                            __fmul_rn(p[q].z, c.z));
                const float dd = __fsub_rn(__fadd_rn(p[q].w, c.w),
                                           __fmul_rn(2.0f, dot));
                push5(dd, idx, d[q], ix[q]);
            }
        }
    }
}

// Wave-shared lagged threshold: min over the 32 segment-lanes of each
// query's partial 5th-best (subset-5th >= union-5th, so this is >= the
// global 5th; the inflated fast filter can never reject a true top-5).
__device__ __forceinline__ void share_tau4(const float4 p[NQ],
                                           const float d[NQ][KNN], float tau[NQ])
{
    float m5[NQ];
    #pragma unroll
    for (int q = 0; q < NQ; ++q) m5[q] = d[q][KNN - 1];
    #pragma unroll
    for (int mask = 2; mask < 64; mask <<= 1)
        #pragma unroll
        for (int q = 0; q < NQ; ++q)
            m5[q] = fminf(m5[q], __shfl_xor(m5[q], mask));
    #pragma unroll
    for (int q = 0; q < NQ; ++q)
        tau[q] = __fsub_rn(m5[q], p[q].w) + 6e-5f;  // inf stays inf
}

__global__ __launch_bounds__(NTHR, 4)
void knn_trace_kernel(const float* __restrict__ pcd, float* __restrict__ trace_out)
{
    __shared__ float4 spts[N_PTS + 8];   // {x,y,z,|p|^2}, swizzled (65,664 B)

    const int b = blockIdx.y;
    const int t = threadIdx.x;
    const float* __restrict__ batch = pcd + (size_t)b * N_PTS * 3;

    // ---- stage batch into LDS, |p|^2 = (x*x + y*y) + z*z ----
    #pragma unroll
    for (int i = 0; i < N_PTS / NTHR; ++i) {
        const int p = t + i * NTHR;
        const float x = batch[p * 3 + 0];
        const float y = batch[p * 3 + 1];
        const float z = batch[p * 3 + 2];
        const float sq = __fadd_rn(__fadd_rn(__fmul_rn(x, x), __fmul_rn(y, y)),
                                   __fmul_rn(z, z));
        spts[swz(p)] = make_float4(x, y, z, sq);
    }
    __syncthreads();

    const int lane = t & 63;
    const int wave = t >> 6;
    const int j    = lane & 1;             // query-slot group
    const int s    = lane >> 1;            // segment 0..31
    const int qbase = blockIdx.x * QPB + wave * QPW + j * NQ;

    float4 p[NQ];                          // query {x,y,z,|q|^2}
    float4 a[NQ];                          // {-2qx,-2qy,-2qz, unused}
    #pragma unroll
    for (int q = 0; q < NQ; ++q) {
        p[q] = spts[swz(qbase + q)];
        a[q] = make_float4(__fmul_rn(-2.0f, p[q].x),
                           __fmul_rn(-2.0f, p[q].y),
                           __fmul_rn(-2.0f, p[q].z), 0.0f);
    }

    float d[NQ][KNN];
    int   ix[NQ][KNN];
    #pragma unroll
    for (int q = 0; q < NQ; ++q)
        #pragma unroll
        for (int r = 0; r < KNN; ++r) { d[q][r] = __builtin_inff(); ix[q][r] = 0x7fffffff; }

    // seg base: swz(s*SEGLEN + m) = s*SEGLEN + (s>>2) + m for m < SEGLEN
    const float4* __restrict__ seg = spts + (s * SEGLEN + (s >> 2));
    const int idx0 = s * SEGLEN;
    float tau[NQ];
    unsigned m[NQ], rr[NQ];

    // ---- seed: exact-push candidates 0..7 (ascending idx), share tau ----
    #pragma unroll
    for (int u = 0; u < 8; ++u) {
        const float4 c = seg[u];
        const int idx = idx0 + u;
        #pragma unroll
        for (int q = 0; q < NQ; ++q) {
            const float dot = __fadd_rn(__fadd_rn(__fmul_rn(p[q].x, c.x),
                                                  __fmul_rn(p[q].y, c.y)),
                                        __fmul_rn(p[q].z, c.z));
            const float dd = __fsub_rn(__fadd_rn(p[q].w, c.w),
                                       __fmul_rn(2.0f, dot));
            push5(dd, idx, d[q], ix[q]);
        }
    }
    share_tau4(p, d, tau);

    // ---- filtered chunks: [8,40) [40,72) [72,104) [104,128) ----
    scan_chunk<32>(seg, 8, a, tau, m);
    #pragma unroll
    for (int q = 0; q < NQ; ++q) rr[q] = __brev(m[q]);
    drain4(rr, idx0 + 8, p, d, ix, spts);
    share_tau4(p, d, tau);

    scan_chunk<32>(seg, 40, a, tau, m);
    #pragma unroll
    for (int q = 0; q < NQ; ++q) rr[q] = __brev(m[q]);
    drain4(rr, idx0 + 40, p, d, ix, spts);
    share_tau4(p, d, tau);

    scan_chunk<32>(seg, 72, a, tau, m);
    #pragma unroll
    for (int q = 0; q < NQ; ++q) rr[q] = __brev(m[q]);
    drain4(rr, idx0 + 72, p, d, ix, spts);
    share_tau4(p, d, tau);

    scan_chunk<24>(seg, 104, a, tau, m);
    #pragma unroll
    for (int q = 0; q < NQ; ++q) rr[q] = __brev(m[q]);
    drain4(rr, idx0 + 104 - 8, p, d, ix, spts);   // base -= (32-LEN)

    // ---- pack keys = (bits(sqrt(max(dd,0))) << 32) | idx, sort 5 ----
    ull key[NQ][KNN];
    #pragma unroll
    for (int q = 0; q < NQ; ++q) {
        #pragma unroll
        for (int r = 0; r < KNN; ++r) {
            const float dist = __fsqrt_rn(fmaxf(d[q][r], 0.0f));
            key[q][r] = ((ull)__float_as_uint(dist) << 32) | (unsigned)ix[q][r];
        }
        sort5(key[q]);
    }

    // ---- butterfly merge across the 32 segment lanes (masks 2..32) ----
    #pragma unroll
    for (int mask = 2; mask < 64; mask <<= 1) {
        #pragma unroll
        for (int q = 0; q < NQ; ++q) {
            ull o[KNN];
            #pragma unroll
            for (int r = 0; r < KNN; ++r) o[r] = __shfl_xor(key[q][r], mask);
            merge5(key[q], o);
        }
    }

    // ---- epilogue: lane j==lane<2 owns queries qbase+0..3 ----
    if (lane < 2) {
        #pragma unroll
        for (int q = 0; q < NQ; ++q) {
            float nx[KNN], ny[KNN], nz[KNN];
            #pragma unroll
            for (int r = 0; r < KNN; ++r) {
                const int sel = (int)(key[q][r] & 0xffffffffull);
                const float4 c = spts[swz(sel)];
                nx[r] = c.x; ny[r] = c.y; nz[r] = c.z;
            }

            float sx = nx[0], sy = ny[0], sz = nz[0];
            #pragma unroll
            for (int r = 1; r < KNN; ++r) {
                sx = __fadd_rn(sx, nx[r]);
                sy = __fadd_rn(sy, ny[r]);
                sz = __fadd_rn(sz, nz[r]);
            }
            const float cx = __fdiv_rn(sx, 5.0f);
            const float cy = __fdiv_rn(sy, 5.0f);
            const float cz = __fdiv_rn(sz, 5.0f);

            float sxx = 0.0f, syy = 0.0f, szz = 0.0f;
            #pragma unroll
            for (int r = 0; r < KNN; ++r) {
                const float dx = __fsub_rn(nx[r], cx);
                const float dy = __fsub_rn(ny[r], cy);
                const float dz = __fsub_rn(nz[r], cz);
                sxx = __fadd_rn(sxx, __fmul_rn(dx, dx));
                syy = __fadd_rn(syy, __fmul_rn(dy, dy));
                szz = __fadd_rn(szz, __fmul_rn(dz, dz));
            }
            const float trace = __fadd_rn(__fadd_rn(__fmul_rn(sxx, 0.25f),
                                                    __fmul_rn(syy, 0.25f)),
                                          __fmul_rn(szz, 0.25f));
            trace_out[(size_t)b * N_PTS + qbase + q] = trace;
        }
    }
}

// Unchanged from rounds 2-4 (passed with absmax 0.0) — keep the reduction
// tree bit-identical.
__global__ __launch_bounds__(256)
void curvature_kernel(const float* __restrict__ trace, float* __restrict__ out)
{
    __shared__ float red[256];
    const int b = blockIdx.x >> 3;
    const int c = blockIdx.x & 7;
    const int t = threadIdx.x;
    const float* __restrict__ tr = trace + (size_t)b * N_PTS;

    float s = 0.0f;
    #pragma unroll
    for (int i = 0; i < N_PTS / 256; ++i)
        s += tr[t + i * 256];
    red[t] = s;
    __syncthreads();
    #pragma unroll
    for (int o = 128; o > 0; o >>= 1) {
        if (t < o) red[t] += red[t + o];
        __syncthreads();
    }
    const float denom = red[0] + 1e-8f;

    float* __restrict__ ob = out + (size_t)b * N_PTS;
    const int x = c * 512 + t;
    ob[x]       = tr[x]       / denom;
    ob[x + 256] = tr[x + 256] / denom;
}

extern "C" void kernel_launch(void* const* d_in, const int* in_sizes, int n_in,
                              void* d_out, int out_size, void* d_ws, size_t ws_size,
                              hipStream_t stream)
{
    (void)in_sizes; (void)n_in; (void)out_size; (void)ws_size;
    const float* pcd = (const float*)d_in[0];   // [8,4096,3] f32
    float* trace = (float*)d_ws;                // [8,4096] f32 scratch
    float* out = (float*)d_out;                 // [8,4096] f32

    dim3 gridA(N_PTS / QPB, BATCH);             // 64 x 8 = 512 blocks (2/CU)
    knn_trace_kernel<<<gridA, NTHR, 0, stream>>>(pcd, trace);
    curvature_kernel<<<BATCH * 8, 256, 0, stream>>>(trace, out);
}

// Round 3
// 115.888 us; speedup vs baseline: 3.1414x; 3.1414x over previous
//
#include <hip/hip_runtime.h>

// MC3DAD kNN(k=5) covariance-trace curvature. B=8, N=4096, f32.
// Round 6: round-4's proven NQ=2 register structure (52 VGPR, no spills)
// with round-5's occupancy geometry and verified math:
//  (1) j=lane&3, s=lane>>2 -> 16 segments x SEGLEN=256, 8 queries/wave,
//      64 queries/block -> 512 blocks = 2 blocks/CU = 16 waves/CU (4/SIMD):
//      2x round 4's latency hiding. LDS 2 x 64.5 KB fits 160 KB.
//  (2) 4 lanes broadcast each candidate address (16 distinct addrs/wave
//      over 8 bank-quads via swizzle) -> cheaper LDS wave-instructions.
//  (3) Pre-scaled queries (-2q exact): filter = 3 chained fma + cmp +
//      mask-add. Proven absmax 0.0 in round 5.
//  (4) Seed-8 exact push + wave-shared tau (subset-5th >= union-5th, same
//      6e-5 inflated margin). Proven absmax 0.0 in round 5.
//  NO NQ=4 arrays, NO q-indexed state in drains (round-5 spill lesson):
//  everything is named p0/p1/d0/d1/... exactly like round 4.
//  Selection machinery bit-identical to rounds 3-5 (absmax 0.0): exact
//  numpy-tree dd recompute, strict-< push5 in ascending index order, final
//  ranking by packed (sqrt-dist, idx) u64 keys, same epilogue arithmetic.

typedef unsigned long long ull;

constexpr int N_PTS  = 4096;
constexpr int BATCH  = 8;
constexpr int KNN    = 5;
constexpr int GSEG   = 16;              // segments (s = lane>>2)
constexpr int SEGLEN = N_PTS / GSEG;    // 256 candidates per lane
constexpr int NTHR   = 512;             // 8 waves
constexpr int QPW    = 8;               // queries per wave (j = lane&3, NQ=2)
constexpr int QPB    = (NTHR / 64) * QPW;   // 64 queries per block

__device__ __forceinline__ int swz(int j) { return j + (j >> 9); } // +16B/512pts

__device__ __forceinline__ ull umin64(ull a, ull b) { return a < b ? a : b; }
__device__ __forceinline__ ull umax64(ull a, ull b) { return a < b ? b : a; }

// Branchless stable insert of (dd,idx) into ascending 5-list (strict <).
// Callers guarantee ascending-index insertion order, so equal-dd entries
// stay in index order (matches jax.lax.top_k stability).
__device__ __forceinline__ void push5(float dd, int idx,
                                      float d[KNN], int ix[KNN])
{
    float ad = dd; int ai = idx;
    #pragma unroll
    for (int p = 0; p < KNN - 1; ++p) {
        const bool lt = ad < d[p];
        const float md = lt ? ad : d[p];
        const int   mi = lt ? ai : ix[p];
        const float xd = lt ? d[p] : ad;
        const int   xi = lt ? ix[p] : ai;
        d[p] = md; ix[p] = mi; ad = xd; ai = xi;
    }
    const bool lt = ad < d[KNN - 1];
    d[KNN - 1]  = lt ? ad : d[KNN - 1];
    ix[KNN - 1] = lt ? ai : ix[KNN - 1];
}

// Merge two ascending sorted 5-lists (u64 lex keys) -> ascending top-5.
__device__ __forceinline__ void merge5(ull a[KNN], const ull b[KNN])
{
    const ull r0 = umin64(a[0], b[0]);
    const ull r1 = umin64(umin64(a[1], b[1]), umax64(a[0], b[0]));
    const ull r2 = umin64(umin64(a[2], b[2]),
                          umin64(umax64(a[1], b[0]), umax64(a[0], b[1])));
    const ull r3 = umin64(umin64(a[3], b[3]),
                   umin64(umax64(a[2], b[0]),
                   umin64(umax64(a[1], b[1]), umax64(a[0], b[2]))));
    const ull r4 = umin64(umin64(a[4], b[4]),
                   umin64(umin64(umax64(a[3], b[0]), umax64(a[2], b[1])),
                          umin64(umax64(a[1], b[2]), umax64(a[0], b[3]))));
    a[0] = r0; a[1] = r1; a[2] = r2; a[3] = r3; a[4] = r4;
}

__device__ __forceinline__ void sort5(ull key[KNN])
{
    #pragma unroll
    for (int i = 0; i < KNN - 1; ++i)
        #pragma unroll
        for (int p = 0; p < KNN - 1 - i; ++p) {
            const ull lo = umin64(key[p], key[p + 1]);
            const ull hi = umax64(key[p], key[p + 1]);
            key[p] = lo; key[p + 1] = hi;
        }
}

// Filtered scan over LEN candidates (4-batched loads). Masks accumulate
// MSB-first: after LEN shifts, bit (LEN-1-u) holds candidate u.
// a = (-2qx,-2qy,-2qz) exact; f = fma(ax,cx, fma(ay,cy, fma(az,cz, cw)))
// approximates dd - qw; tau is the lagged inflated threshold.
template<int LEN>
__device__ __forceinline__ void scan_chunk(const float4* __restrict__ seg, int start,
                                           const float4 a0, const float4 a1,
                                           const float tau0, const float tau1,
                                           unsigned& m0, unsigned& m1)
{
    unsigned x = 0u, y = 0u;
    #pragma unroll
    for (int g = 0; g < LEN; g += 4) {
        float4 cb[4];
        #pragma unroll
        for (int u = 0; u < 4; ++u) cb[u] = seg[start + g + u];
        #pragma unroll
        for (int u = 0; u < 4; ++u) {
            const float f0 = fmaf(a0.x, cb[u].x,
                             fmaf(a0.y, cb[u].y,
                             fmaf(a0.z, cb[u].z, cb[u].w)));
            const float f1 = fmaf(a1.x, cb[u].x,
                             fmaf(a1.y, cb[u].y,
                             fmaf(a1.z, cb[u].z, cb[u].w)));
            x = (x << 1) | (f0 < tau0 ? 1u : 0u);
            y = (y << 1) | (f1 < tau1 ? 1u : 0u);
        }
    }
    m0 = x; m1 = y;
}

// Drain bit-reversed keep masks for both queries. ctz over the reversed mask
// walks candidates in ascending index order (idx = base + bitpos). Exact
// numpy-tree dd recompute, identical to the proven round-3/4 drain.
__device__ __forceinline__ void drain_pair(unsigned r0, unsigned r1, int base,
                                           const float4 p0, const float4 p1,
                                           float* __restrict__ d0, int* __restrict__ i0,
                                           float* __restrict__ d1, int* __restrict__ i1,
                                           const float4* __restrict__ pts)
{
    while (__any((r0 | r1) != 0u)) {
        if (r0) {
            const int bpos = __builtin_ctz(r0);
            r0 &= r0 - 1;
            const int idx = base + bpos;
            const float4 c = pts[swz(idx)];
            const float dot = __fadd_rn(__fadd_rn(__fmul_rn(p0.x, c.x),
                                                  __fmul_rn(p0.y, c.y)),
                                        __fmul_rn(p0.z, c.z));
            const float dd = __fsub_rn(__fadd_rn(p0.w, c.w),
                                       __fmul_rn(2.0f, dot));
            push5(dd, idx, d0, i0);
        }
        if (r1) {
            const int bpos = __builtin_ctz(r1);
            r1 &= r1 - 1;
            const int idx = base + bpos;
            const float4 c = pts[swz(idx)];
            const float dot = __fadd_rn(__fadd_rn(__fmul_rn(p1.x, c.x),
                                                  __fmul_rn(p1.y, c.y)),
                                        __fmul_rn(p1.z, c.z));
            const float dd = __fsub_rn(__fadd_rn(p1.w, c.w),
                                       __fmul_rn(2.0f, dot));
            push5(dd, idx, d1, i1);
        }
    }
}

// Wave-shared lagged threshold: min over the 16 segment-lanes of each
// query's partial 5th-best (subset-5th >= union-5th, so this is >= the
// global 5th; the inflated fast filter can never reject a true top-5).
__device__ __forceinline__ void share_tau(const float4 p0, const float4 p1,
                                          float d0_4, float d1_4,
                                          float& tau0, float& tau1)
{
    #pragma unroll
    for (int mask = 4; mask < 64; mask <<= 1) {
        d0_4 = fminf(d0_4, __shfl_xor(d0_4, mask));
        d1_4 = fminf(d1_4, __shfl_xor(d1_4, mask));
    }
    tau0 = __fsub_rn(d0_4, p0.w) + 6e-5f;  // inf stays inf
    tau1 = __fsub_rn(d1_4, p1.w) + 6e-5f;
}

__global__ __launch_bounds__(NTHR, 2)
void knn_trace_kernel(const float* __restrict__ pcd, float* __restrict__ trace_out)
{
    __shared__ float4 spts[N_PTS + 8];   // {x,y,z,|p|^2}, swizzled (65,664 B)

    const int b = blockIdx.y;
    const int t = threadIdx.x;
    const float* __restrict__ batch = pcd + (size_t)b * N_PTS * 3;

    // ---- stage batch into LDS, |p|^2 = (x*x + y*y) + z*z ----
    #pragma unroll
    for (int i = 0; i < N_PTS / NTHR; ++i) {
        const int p = t + i * NTHR;
        const float x = batch[p * 3 + 0];
        const float y = batch[p * 3 + 1];
        const float z = batch[p * 3 + 2];
        const float sq = __fadd_rn(__fadd_rn(__fmul_rn(x, x), __fmul_rn(y, y)),
                                   __fmul_rn(z, z));
        spts[swz(p)] = make_float4(x, y, z, sq);
    }
    __syncthreads();

    const int lane = t & 63;
    const int wave = t >> 6;
    const int j    = lane & 3;             // query-pair slot 0..3
    const int s    = lane >> 2;            // segment 0..15
    const int qbase = blockIdx.x * QPB + wave * QPW + j * 2;

    const float4 p0 = spts[swz(qbase + 0)];
    const float4 p1 = spts[swz(qbase + 1)];
    // exact: *2 is lossless in fp32
    const float4 a0 = make_float4(__fmul_rn(-2.0f, p0.x), __fmul_rn(-2.0f, p0.y),
                                  __fmul_rn(-2.0f, p0.z), 0.0f);
    const float4 a1 = make_float4(__fmul_rn(-2.0f, p1.x), __fmul_rn(-2.0f, p1.y),
                                  __fmul_rn(-2.0f, p1.z), 0.0f);

    float d0[KNN], d1[KNN];
    int   i0[KNN], i1[KNN];
    #pragma unroll
    for (int r = 0; r < KNN; ++r) {
        d0[r] = __builtin_inff(); i0[r] = 0x7fffffff;
        d1[r] = __builtin_inff(); i1[r] = 0x7fffffff;
    }

    // seg base: swz(s*SEGLEN + m) = s*SEGLEN + (s>>1) + m for m in [0,256)
    const float4* __restrict__ seg = spts + (s * SEGLEN + (s >> 1));
    const int idx0 = s * SEGLEN;
    float tau0, tau1;
    unsigned m0, m1;

    // ---- seed: exact-push candidates 0..7 (ascending idx), share tau ----
    #pragma unroll
    for (int u = 0; u < 8; ++u) {
        const float4 c = seg[u];
        const int idx = idx0 + u;
        {
            const float dot = __fadd_rn(__fadd_rn(__fmul_rn(p0.x, c.x),
                                                  __fmul_rn(p0.y, c.y)),
                                        __fmul_rn(p0.z, c.z));
            const float dd = __fsub_rn(__fadd_rn(p0.w, c.w),
                                       __fmul_rn(2.0f, dot));
            push5(dd, idx, d0, i0);
        }
        {
            const float dot = __fadd_rn(__fadd_rn(__fmul_rn(p1.x, c.x),
                                                  __fmul_rn(p1.y, c.y)),
                                        __fmul_rn(p1.z, c.z));
            const float dd = __fsub_rn(__fadd_rn(p1.w, c.w),
                                       __fmul_rn(2.0f, dot));
            push5(dd, idx, d1, i1);
        }
    }
    share_tau(p0, p1, d0[KNN - 1], d1[KNN - 1], tau0, tau1);

    // ---- filtered chunks: 7 x 32 over [8,232), then 24 over [232,256) ----
    #pragma unroll 1
    for (int c = 0; c < 7; ++c) {
        const int s0 = 8 + c * 32;
        scan_chunk<32>(seg, s0, a0, a1, tau0, tau1, m0, m1);
        drain_pair(__brev(m0), __brev(m1), idx0 + s0, p0, p1, d0, i0, d1, i1, spts);
        share_tau(p0, p1, d0[KNN - 1], d1[KNN - 1], tau0, tau1);
    }
    scan_chunk<24>(seg, 232, a0, a1, tau0, tau1, m0, m1);
    drain_pair(__brev(m0), __brev(m1), idx0 + 232 - 8, p0, p1, d0, i0, d1, i1, spts);

    // ---- pack keys = (bits(sqrt(max(dd,0))) << 32) | idx, sort 5 ----
    ull kA[KNN], kB[KNN];
    #pragma unroll
    for (int r = 0; r < KNN; ++r) {
        const float da = __fsqrt_rn(fmaxf(d0[r], 0.0f));
        kA[r] = ((ull)__float_as_uint(da) << 32) | (unsigned)i0[r];
        const float db = __fsqrt_rn(fmaxf(d1[r], 0.0f));
        kB[r] = ((ull)__float_as_uint(db) << 32) | (unsigned)i1[r];
    }
    sort5(kA);
    sort5(kB);

    // ---- butterfly merge across the 16 segment lanes (masks 4..32) ----
    #pragma unroll
    for (int mask = 4; mask < 64; mask <<= 1) {
        ull oA[KNN], oB[KNN];
        #pragma unroll
        for (int r = 0; r < KNN; ++r) {
            oA[r] = __shfl_xor(kA[r], mask);
            oB[r] = __shfl_xor(kB[r], mask);
        }
        merge5(kA, oA);
        merge5(kB, oB);
    }

    // ---- epilogue: lanes 0..3 own queries qbase+0 (kA) and qbase+1 (kB) --
    if (lane < 4) {
        #pragma unroll
        for (int which = 0; which < 2; ++which) {
            float nx[KNN], ny[KNN], nz[KNN];
            #pragma unroll
            for (int r = 0; r < KNN; ++r) {
                const int sel = (int)((which ? kB[r] : kA[r]) & 0xffffffffull);
                const float4 c = spts[swz(sel)];
                nx[r] = c.x; ny[r] = c.y; nz[r] = c.z;
            }

            float sx = nx[0], sy = ny[0], sz = nz[0];
            #pragma unroll
            for (int r = 1; r < KNN; ++r) {
                sx = __fadd_rn(sx, nx[r]);
                sy = __fadd_rn(sy, ny[r]);
                sz = __fadd_rn(sz, nz[r]);
            }
            const float cx = __fdiv_rn(sx, 5.0f);
            const float cy = __fdiv_rn(sy, 5.0f);
            const float cz = __fdiv_rn(sz, 5.0f);

            float sxx = 0.0f, syy = 0.0f, szz = 0.0f;
            #pragma unroll
            for (int r = 0; r < KNN; ++r) {
                const float dx = __fsub_rn(nx[r], cx);
                const float dy = __fsub_rn(ny[r], cy);
                const float dz = __fsub_rn(nz[r], cz);
                sxx = __fadd_rn(sxx, __fmul_rn(dx, dx));
                syy = __fadd_rn(syy, __fmul_rn(dy, dy));
                szz = __fadd_rn(szz, __fmul_rn(dz, dz));
            }
            const float trace = __fadd_rn(__fadd_rn(__fmul_rn(sxx, 0.25f),
                                                    __fmul_rn(syy, 0.25f)),
                                          __fmul_rn(szz, 0.25f));
            trace_out[(size_t)b * N_PTS + qbase + which] = trace;
        }
    }
}

// Unchanged from rounds 2-5 (passed with absmax 0.0) — keep the reduction
// tree bit-identical.
__global__ __launch_bounds__(256)
void curvature_kernel(const float* __restrict__ trace, float* __restrict__ out)
{
    __shared__ float red[256];
    const int b = blockIdx.x >> 3;
    const int c = blockIdx.x & 7;
    const int t = threadIdx.x;
    const float* __restrict__ tr = trace + (size_t)b * N_PTS;

    float s = 0.0f;
    #pragma unroll
    for (int i = 0; i < N_PTS / 256; ++i)
        s += tr[t + i * 256];
    red[t] = s;
    __syncthreads();
    #pragma unroll
    for (int o = 128; o > 0; o >>= 1) {
        if (t < o) red[t] += red[t + o];
        __syncthreads();
    }
    const float denom = red[0] + 1e-8f;

    float* __restrict__ ob = out + (size_t)b * N_PTS;
    const int x = c * 512 + t;
    ob[x]       = tr[x]       / denom;
    ob[x + 256] = tr[x + 256] / denom;
}

extern "C" void kernel_launch(void* const* d_in, const int* in_sizes, int n_in,
                              void* d_out, int out_size, void* d_ws, size_t ws_size,
                              hipStream_t stream)
{
    (void)in_sizes; (void)n_in; (void)out_size; (void)ws_size;
    const float* pcd = (const float*)d_in[0];   // [8,4096,3] f32
    float* trace = (float*)d_ws;                // [8,4096] f32 scratch
    float* out = (float*)d_out;                 // [8,4096] f32

    dim3 gridA(N_PTS / QPB, BATCH);             // 64 x 8 = 512 blocks (2/CU)
    knn_trace_kernel<<<gridA, NTHR, 0, stream>>>(pcd, trace);
    curvature_kernel<<<BATCH * 8, 256, 0, stream>>>(trace, out);
}